// Round 16
// baseline (460.073 us; speedup 1.0000x reference)
//
#include <hip/hip_runtime.h>
#include <stdint.h>

// ---------------------------------------------------------------------------
// Net_27891517620298: edge-popup supermask CNN forward.
// R15: R14 with ONE isolated change: conv LDS pixel stride PSTR 40 -> 34,
// shrinking sIn below 40 KB => 4 blocks/CU (16 waves, was 12). Bank math:
// B-frag reads lane-stride 68 words ≡ 2 mod 32 -> 16 distinct even banks,
// 2-way overlap = free. Everything else identical to R14 (3-pass 11/11/9
// radix select, R9 convs/FCs, XCD-aligned grids).
// ---------------------------------------------------------------------------

typedef __attribute__((ext_vector_type(8))) short short8;
typedef __attribute__((ext_vector_type(4))) short short4v;
typedef __attribute__((ext_vector_type(4))) float floatx4;

__device__ __forceinline__ unsigned short f2bf(float f) {
    unsigned u = __float_as_uint(f);
    u += 0x7fffu + ((u >> 16) & 1u);   // round-to-nearest-even
    return (unsigned short)(u >> 16);
}

// ---------------- exact top-k selection: 3-pass 11/11/9-bit radix -----------
constexpr unsigned CUM0 = 3456u;
constexpr unsigned CUM1 = 298368u;
constexpr unsigned CUM2 = 1478016u;
constexpr unsigned CUM3 = 2002304u;
constexpr unsigned STOT = 2012544u;
constexpr int NBH = 128;

__device__ __forceinline__ int find_tensor(unsigned idx, unsigned& li) {
    if (idx < CUM0) { li = idx;        return 0; }
    if (idx < CUM1) { li = idx - CUM0; return 1; }
    if (idx < CUM2) { li = idx - CUM1; return 2; }
    if (idx < CUM3) { li = idx - CUM2; return 3; }
    li = idx - CUM3; return 4;
}

__global__ __launch_bounds__(256) void hist11(const float* __restrict__ s0,
                                              const float* __restrict__ s1,
                                              const float* __restrict__ s2,
                                              const float* __restrict__ s3,
                                              const float* __restrict__ s4,
                                              const unsigned* __restrict__ P,
                                              unsigned* __restrict__ ghist, int pass) {
    __shared__ unsigned lh[10240];   // up to 2048 bins x 5 tensors
    const int tid = threadIdx.x;
    const int NB = (pass == 2) ? 512 : 2048;
    for (int i = tid; i < NB * 5; i += 256) lh[i] = 0;
    __syncthreads();

    unsigned pref[5];
    #pragma unroll
    for (int t = 0; t < 5; t++) pref[t] = pass ? P[t] : 0u;
    const int fsh = (pass == 1) ? 20 : 9;   // filter shift for pass>=1

    for (unsigned idx = blockIdx.x * 256u + tid; idx < STOT; idx += NBH * 256u) {
        unsigned li; int t = find_tensor(idx, li);
        const float* sp = t == 0 ? s0 : t == 1 ? s1 : t == 2 ? s2 : t == 3 ? s3 : s4;
        unsigned key = __float_as_uint(sp[li]) & 0x7fffffffu;
        bool ok = (pass == 0) || ((key >> fsh) == pref[t]);
        if (ok) {
            unsigned bin = (pass == 0) ? (key >> 20)
                         : (pass == 1) ? ((key >> 9) & 2047u)
                                       : (key & 511u);
            atomicAdd(&lh[(unsigned)t * NB + bin], 1u);
        }
    }
    __syncthreads();
    const int goff = (pass == 0) ? 0 : (pass == 1) ? 10240 : 20480;
    for (int i = tid; i < NB * 5; i += 256) {
        unsigned v = lh[i];
        if (v) atomicAdd(&ghist[goff + i], v);
    }
}

__global__ __launch_bounds__(256) void find11(const unsigned* __restrict__ ghist,
                                              unsigned* __restrict__ P,
                                              unsigned* __restrict__ targ, int pass) {
    const int t = blockIdx.x;
    const int tid = threadIdx.x;
    const int NB = (pass == 2) ? 512 : 2048;
    const int goff = (pass == 0) ? 0 : (pass == 1) ? 10240 : 20480;
    const int seg = NB / 256;   // 8 or 2
    __shared__ unsigned bins[2048];
    __shared__ unsigned part[256];
    for (int i = tid; i < NB; i += 256) bins[i] = ghist[goff + t * NB + i];
    __syncthreads();
    unsigned s = 0;
    for (int j = 0; j < seg; j++) s += bins[tid * seg + j];
    part[tid] = s;
    __syncthreads();
    if (tid == 0) {
        unsigned n = t == 0 ? 3456u : t == 1 ? 294912u : t == 2 ? 1179648u
                   : t == 3 ? 524288u : 10240u;
        unsigned target = (pass == 0) ? (n >> 1) : targ[t];
        unsigned cum = 0; int q = 0;
        for (; q < 256; q++) { unsigned c = part[q]; if (cum + c > target) break; cum += c; }
        int b = q * seg;
        for (;; b++) { unsigned c = bins[b]; if (cum + c > target) break; cum += c; }
        targ[t] = target - cum;
        if (pass == 0)      P[t] = (unsigned)b;
        else if (pass == 1) P[t] = (P[t] << 11) | (unsigned)b;
        else                P[t] = (P[t] << 9) | (unsigned)b;
    }
}

// Fused: mask by threshold; conv1/fc weights stay fp32; conv2/3 weights go
// bf16 in MFMA-friendly [e][k][c] layout. Also zeroes `pooled`.
__global__ void mask_reorder(const float* __restrict__ w0, const float* __restrict__ w1,
                             const float* __restrict__ w2, const float* __restrict__ w3,
                             const float* __restrict__ w4,
                             const float* __restrict__ s0, const float* __restrict__ s1,
                             const float* __restrict__ s2, const float* __restrict__ s3,
                             const float* __restrict__ s4,
                             const unsigned* __restrict__ T,
                             float* __restrict__ wm1,
                             unsigned short* __restrict__ A2,
                             unsigned short* __restrict__ A3,
                             float* __restrict__ fwm1, float* __restrict__ fwm2,
                             float* __restrict__ pooled) {
    unsigned idx = blockIdx.x * 256u + threadIdx.x;
    if (idx >= STOT) return;
    if (idx < 32768u) pooled[idx] = 0.f;
    unsigned li; int t = find_tensor(idx, li);
    const float* sp = t == 0 ? s0 : t == 1 ? s1 : t == 2 ? s2 : t == 3 ? s3 : s4;
    const float* wp = t == 0 ? w0 : t == 1 ? w1 : t == 2 ? w2 : t == 3 ? w3 : w4;
    unsigned key = __float_as_uint(sp[li]) & 0x7fffffffu;
    float val = (key >= T[t]) ? wp[li] : 0.f;
    if (t == 0) {
        wm1[li] = val;
    } else if (t == 1) {           // w2 [256][128][3][3] -> A2 [e][256][128]
        unsigned k = li / 1152u, r = li - k * 1152u;
        unsigned c = r / 9u, e = r - c * 9u;
        A2[((size_t)e * 256u + k) * 128u + c] = f2bf(val);
    } else if (t == 2) {           // w3 [512][256][3][3] -> A3 [e][512][256]
        unsigned k = li / 2304u, r = li - k * 2304u;
        unsigned c = r / 9u, e = r - c * 9u;
        A3[((size_t)e * 512u + k) * 256u + c] = f2bf(val);
    } else if (t == 3) {
        fwm1[li] = val;
    } else {
        fwm2[li] = val;
    }
}

// ---------------- conv1: direct 3x3 fp32 -> bf16 NHWC -----------------------
template <int C, int H, int W, int K, int TX, int TY, int KT>
__global__ __launch_bounds__(TX* TY) void conv_direct(const float* __restrict__ in,
                                                      const float* __restrict__ wm,
                                                      const float* __restrict__ bias,
                                                      unsigned short* __restrict__ out) {
    constexpr int TILW = TX * 2, TILH = TY * 2;
    constexpr int ITW = TILW + 2, ITH = TILH + 2;
    constexpr int NTHREADS = TX * TY;
    constexpr int NLOAD = (ITH * ITW + NTHREADS - 1) / NTHREADS;
    constexpr int KG = K / KT;

    __shared__ float sIn[ITH * ITW];
    __shared__ float sW[9 * KT];

    const int tid = threadIdx.x;
    const int tx = tid % TX, ty = tid / TX;
    const int kg = blockIdx.z % KG, n = blockIdx.z / KG;
    const int ox0 = blockIdx.x * TILW, oy0 = blockIdx.y * TILH;
    const int ix0 = ox0 - 1, iy0 = oy0 - 1;

    const float* inN = in + (size_t)n * C * H * W;
    const float* wkg = wm + (size_t)kg * KT * C * 9;

    int goff[NLOAD];
    #pragma unroll
    for (int i = 0; i < NLOAD; i++) {
        int idx = tid + i * NTHREADS;
        if (idx < ITH * ITW) {
            int r = idx / ITW, col = idx % ITW;
            int gy = iy0 + r, gx = ix0 + col;
            goff[i] = (gy >= 0 && gy < H && gx >= 0 && gx < W) ? (gy * W + gx) : -1;
        } else goff[i] = -2;
    }

    float acc[2][2][KT];
    #pragma unroll
    for (int py = 0; py < 2; py++)
        #pragma unroll
        for (int px = 0; px < 2; px++)
            #pragma unroll
            for (int j = 0; j < KT; j++) acc[py][px][j] = 0.f;

    for (int c = 0; c < C; c++) {
        const float* inC = inN + (size_t)c * H * W;
        #pragma unroll
        for (int i = 0; i < NLOAD; i++) {
            int g = goff[i];
            if (g >= -1) sIn[tid + i * NTHREADS] = (g >= 0) ? inC[g] : 0.f;
        }
        for (int i = tid; i < 9 * KT; i += NTHREADS) {
            int e = i / KT, j = i % KT;
            sW[i] = wkg[j * C * 9 + c * 9 + e];
        }
        __syncthreads();

        float vin[4][4];
        const float* base = &sIn[(ty * 2) * ITW + tx * 2];
        #pragma unroll
        for (int r = 0; r < 4; r++)
            #pragma unroll
            for (int cc = 0; cc < 4; cc++) vin[r][cc] = base[r * ITW + cc];

        #pragma unroll
        for (int e = 0; e < 9; e++) {
            const int dy = e / 3, dx = e % 3;
            #pragma unroll
            for (int j = 0; j < KT; j++) {
                float wv = sW[e * KT + j];
                #pragma unroll
                for (int py = 0; py < 2; py++)
                    #pragma unroll
                    for (int px = 0; px < 2; px++)
                        acc[py][px][j] = fmaf(vin[py + dy][px + dx], wv, acc[py][px][j]);
            }
        }
        __syncthreads();
    }

    float bj[KT];
    #pragma unroll
    for (int j = 0; j < KT; j++) bj[j] = bias[kg * KT + j];
    #pragma unroll
    for (int py = 0; py < 2; py++)
        #pragma unroll
        for (int px = 0; px < 2; px++) {
            int oy = oy0 + ty * 2 + py, ox = ox0 + tx * 2 + px;
            short8 v;
            #pragma unroll
            for (int j = 0; j < KT; j++) {
                float t = acc[py][px][j] + bj[j];
                v[j] = (short)f2bf(t > 0.f ? t : 0.f);
            }
            *(short8*)(out + ((size_t)(n * H + oy) * W + ox) * K + kg * KT) = v;
        }
}

// ---------------- conv2/conv3: NHWC MFMA, B in LDS, A prefetched ------------
// stride-2 3x3 conv, bf16 NHWC input. Block = 4 waves; tile 128 k x 128 pix.
// Wave: 32 k (2 fm) x 128 pix (8 fn). Per 32-ch chunk: stage input tile once
// (the ONLY barriers: 2 per chunk), then 9 taps x {8 B ds_read_b128, 16 MFMA}
// with A-frags (2/tap) global->VGPR prefetched one tap ahead (L2-resident).
// PSTR=34: sIn < 40 KB -> 4 blocks/CU; B-read lane stride 68 words ≡ 2 mod 32
// -> 2-way bank overlap (free). Grid dim3(pt,kb,n): input-sharing pairs are
// 8 apart in linear id -> same XCD (measured: FETCH 57 vs 135 MB otherwise).
template <int C, int H, int W, int KOUT, bool POOL>
__global__ __launch_bounds__(256) void conv_mfma(const unsigned short* __restrict__ in,
                                                 const unsigned short* __restrict__ A,
                                                 const float* __restrict__ bias,
                                                 void* __restrict__ outv) {
    constexpr int OH = H / 2, OW = W / 2;
    constexpr int PR = 128 / OW;          // output rows per 128-pixel tile
    constexpr int RH = 2 * PR + 1;        // input rows needed
    constexpr int IW = W + 1;             // input cols needed
    constexpr int NC = C / 32;
    constexpr int PSTR = 34;              // shorts per pixel (32 + 2 pad)
    constexpr int NSLOT = RH * IW * 4;    // 16B staging chunks
    constexpr int SLMAX = (NSLOT + 255) / 256;

    __shared__ unsigned short sIn[RH * IW * PSTR];

    const int tid = threadIdx.x;
    const int lane = tid & 63;
    const int wv = tid >> 6;
    const int l15 = lane & 15;
    const int quad = lane >> 4;
    const int pt = blockIdx.x, kb = blockIdx.y, n = blockIdx.z;
    const int k0 = kb * 128;
    const int oy0 = pt * PR;
    const int g0y = 2 * oy0 - 1;
    const int mw = wv * 32;               // wave's 32 output-channel rows

    // staging slots (chunk-invariant): slot s -> (pix = s>>2, q = s&3)
    int goff[SLMAX], slds[SLMAX];
    #pragma unroll
    for (int i = 0; i < SLMAX; i++) {
        int s = tid + i * 256;
        if (s < NSLOT) {
            int q = s & 3, pix = s >> 2;
            int ix = pix % IW, iy = pix / IW;
            int gy = g0y + iy, gx = ix - 1;
            slds[i] = pix * PSTR + q * 8;
            goff[i] = (gy >= 0 && gy < H && gx >= 0) ? ((gy * W + gx) * C + q * 8) : -1;
        } else { goff[i] = -2; slds[i] = 0; }
    }

    // B-frag pixel bases: frag fn = pixels fn*16 + l15
    int pB[8];
    #pragma unroll
    for (int fn = 0; fn < 8; fn++) {
        int p = fn * 16 + l15;
        int oyl = p / OW, oxl = p % OW;
        pB[fn] = (oyl * 2 * IW + oxl * 2) * PSTR + quad * 8;
    }

    const unsigned short* inN = in + (size_t)n * H * W * C;

    floatx4 acc[2][8];
    #pragma unroll
    for (int fm = 0; fm < 2; fm++)
        #pragma unroll
        for (int fn = 0; fn < 8; fn++) acc[fm][fn] = (floatx4){0.f, 0.f, 0.f, 0.f};

    for (int cc = 0; cc < NC; cc++) {
        __syncthreads();   // previous chunk's readers done
        const int cof = cc * 32;
        #pragma unroll
        for (int i = 0; i < SLMAX; i++) {
            int g = goff[i];
            if (g >= 0) {
                *(short8*)&sIn[slds[i]] = *(const short8*)(inN + g + cof);
            } else if (g == -1 && cc == 0) {
                *(short8*)&sIn[slds[i]] = (short8){0, 0, 0, 0, 0, 0, 0, 0};
            }
        }
        __syncthreads();

        // A-frag base for this wave/lane: A[e][k0+mw+l15+fm*16][cof+quad*8]
        const unsigned short* Abase = A + (size_t)(k0 + mw + l15) * C + cof + quad * 8;
        const size_t estr = (size_t)KOUT * C;

        // prefetch tap 0
        short8 a0 = *(const short8*)(Abase);
        short8 a1 = *(const short8*)(Abase + 16 * C);

        #pragma unroll 1
        for (int e = 0; e < 9; e++) {
            short8 ac0 = a0, ac1 = a1;
            if (e < 8) {   // prefetch next tap while computing this one
                a0 = *(const short8*)(Abase + (size_t)(e + 1) * estr);
                a1 = *(const short8*)(Abase + (size_t)(e + 1) * estr + 16 * C);
            }
            const int dy = e / 3, dx = e - dy * 3;
            const int boff = (dy * IW + dx) * PSTR;
            short8 bfr[8];
            #pragma unroll
            for (int fn = 0; fn < 8; fn++)
                bfr[fn] = *(const short8*)&sIn[pB[fn] + boff];
            #pragma unroll
            for (int fn = 0; fn < 8; fn++) {
                acc[0][fn] = __builtin_amdgcn_mfma_f32_16x16x32_bf16(ac0, bfr[fn], acc[0][fn], 0, 0, 0);
                acc[1][fn] = __builtin_amdgcn_mfma_f32_16x16x32_bf16(ac1, bfr[fn], acc[1][fn], 0, 0, 0);
            }
        }
    }

    if (!POOL) {
        unsigned short* out = (unsigned short*)outv;
        #pragma unroll
        for (int fm = 0; fm < 2; fm++) {
            const int k4 = k0 + mw + fm * 16 + quad * 4;
            float b0 = bias[k4], b1 = bias[k4 + 1], b2 = bias[k4 + 2], b3 = bias[k4 + 3];
            #pragma unroll
            for (int fn = 0; fn < 8; fn++) {
                int p = fn * 16 + l15;
                int oy = oy0 + p / OW, ox = p % OW;
                float v0 = acc[fm][fn][0] + b0, v1 = acc[fm][fn][1] + b1;
                float v2 = acc[fm][fn][2] + b2, v3 = acc[fm][fn][3] + b3;
                short4v v;
                v[0] = (short)f2bf(v0 > 0.f ? v0 : 0.f);
                v[1] = (short)f2bf(v1 > 0.f ? v1 : 0.f);
                v[2] = (short)f2bf(v2 > 0.f ? v2 : 0.f);
                v[3] = (short)f2bf(v3 > 0.f ? v3 : 0.f);
                *(short4v*)(out + ((size_t)(n * OH + oy) * OW + ox) * KOUT + k4) = v;
            }
        }
    } else {
        float* out = (float*)outv;
        #pragma unroll
        for (int fm = 0; fm < 2; fm++) {
            #pragma unroll
            for (int reg = 0; reg < 4; reg++) {
                int k = k0 + mw + fm * 16 + quad * 4 + reg;
                float bv = bias[k];
                float s = 0.f;
                #pragma unroll
                for (int fn = 0; fn < 8; fn++) {
                    float v = acc[fm][fn][reg] + bv;
                    s += v > 0.f ? v : 0.f;
                }
                s += __shfl_xor(s, 1); s += __shfl_xor(s, 2);
                s += __shfl_xor(s, 4); s += __shfl_xor(s, 8);
                if (l15 == 0) atomicAdd(&out[n * KOUT + k], s * (1.0f / (OH * OW)));
            }
        }
    }
}

// ---------------- FCs (fp32, tiny; R9 versions) -----------------------------
__global__ void fc1_kernel(const float* __restrict__ pooled, const float* __restrict__ w,
                           const float* __restrict__ b, float* __restrict__ out) {
    int t = blockIdx.x * 256 + threadIdx.x;
    int o = t & 1023, n = t >> 10;
    const float4* w4 = (const float4*)(w + (size_t)o * 512);
    const float4* p4 = (const float4*)(pooled + (size_t)n * 512);
    float acc = 0.f;
    for (int i = 0; i < 128; i++) {
        float4 a = p4[i], ww = w4[i];
        acc += a.x * ww.x + a.y * ww.y + a.z * ww.z + a.w * ww.w;
    }
    acc += b[o];
    out[t] = acc > 0.f ? acc : 0.f;
}

__global__ void fc2_kernel(const float* __restrict__ h, const float* __restrict__ w,
                           const float* __restrict__ b, float* __restrict__ out) {
    int n = blockIdx.x, tid = threadIdx.x;
    __shared__ float redw[40];
    const float4* h4 = (const float4*)(h + (size_t)n * 1024);
    float4 a = h4[tid];
    for (int o = 0; o < 10; o++) {
        const float4* w4 = (const float4*)(w + (size_t)o * 1024);
        float4 ww = w4[tid];
        float v = a.x * ww.x + a.y * ww.y + a.z * ww.z + a.w * ww.w;
        for (int off = 32; off > 0; off >>= 1) v += __shfl_down(v, off);
        if ((tid & 63) == 0) redw[o * 4 + (tid >> 6)] = v;
    }
    __syncthreads();
    if (tid < 10) {
        float s = redw[tid * 4] + redw[tid * 4 + 1] + redw[tid * 4 + 2] + redw[tid * 4 + 3] + b[tid];
        out[n * 10 + tid] = s;
    }
}

extern "C" void kernel_launch(void* const* d_in, const int* in_sizes, int n_in,
                              void* d_out, int out_size, void* d_ws, size_t ws_size,
                              hipStream_t stream) {
    const float* x   = (const float*)d_in[0];
    const float* w1  = (const float*)d_in[1];
    const float* s1  = (const float*)d_in[2];
    const float* b1  = (const float*)d_in[3];
    const float* w2  = (const float*)d_in[4];
    const float* s2  = (const float*)d_in[5];
    const float* b2  = (const float*)d_in[6];
    const float* w3  = (const float*)d_in[7];
    const float* s3  = (const float*)d_in[8];
    const float* b3  = (const float*)d_in[9];
    const float* fw1 = (const float*)d_in[10];
    const float* fs1 = (const float*)d_in[11];
    const float* fb1 = (const float*)d_in[12];
    const float* fw2 = (const float*)d_in[13];
    const float* fs2 = (const float*)d_in[14];
    const float* fb2 = (const float*)d_in[15];
    float* out = (float*)d_out;

    char* ws = (char*)d_ws;
    size_t off = 0;
    auto alloc = [&](size_t bytes) -> char* {
        char* p = ws + off;
        off = (off + bytes + 255) & ~(size_t)255;
        return p;
    };
    unsigned* ghist = (unsigned*)alloc(23040ull * 4);   // 2048*5 + 2048*5 + 512*5
    unsigned* P     = (unsigned*)alloc(64);
    unsigned* targ  = (unsigned*)alloc(64);
    float* wm1  = (float*)alloc(3456ull * 4);
    float* fwm1 = (float*)alloc(524288ull * 4);
    float* fwm2 = (float*)alloc(10240ull * 4);
    unsigned short* A2 = (unsigned short*)alloc(294912ull * 2);   // bf16 [9][256][128]
    unsigned short* A3 = (unsigned short*)alloc(1179648ull * 2);  // bf16 [9][512][256]
    unsigned short* h1 = (unsigned short*)alloc(33554432ull * 2); // bf16 NHWC 64x64x64x128
    unsigned short* h2 = (unsigned short*)alloc(16777216ull * 2); // bf16 NHWC 64x32x32x256
    float* pooled = (float*)alloc(32768ull * 4);                  // 64x512
    float* fc1h   = (float*)alloc(65536ull * 4);                  // 64x1024
    if (off > ws_size) return;

    (void)hipMemsetAsync(ghist, 0, 23040ull * 4, stream);

    for (int pass = 0; pass < 3; pass++) {
        hist11<<<NBH, 256, 0, stream>>>(s1, s2, s3, fs1, fs2, P, ghist, pass);
        find11<<<5, 256, 0, stream>>>(ghist, P, targ, pass);
    }
    int gs = (STOT + 255) / 256;
    mask_reorder<<<gs, 256, 0, stream>>>(w1, w2, w3, fw1, fw2, s1, s2, s3, fs1, fs2, P,
                                         wm1, A2, A3, fwm1, fwm2, pooled);

    // conv1: 3->128, 64x64, stride 1, direct fp32 -> bf16 NHWC h1
    conv_direct<3, 64, 64, 128, 16, 16, 8>
        <<<dim3(2, 2, 64 * 16), 256, 0, stream>>>(x, wm1, b1, h1);
    // conv2: 128->256, 64x64 -> 32x32 NHWC. 8 pixel tiles x 2 k tiles x 64 n
    conv_mfma<128, 64, 64, 256, false>
        <<<dim3(8, 2, 64), 256, 0, stream>>>(h1, A2, b2, h2);
    // conv3: 256->512, 32x32 -> 16x16, fused GAP. 2 pixel tiles x 4 k x 64 n
    conv_mfma<256, 32, 32, 512, true>
        <<<dim3(2, 4, 64), 256, 0, stream>>>(h2, A3, b3, pooled);

    fc1_kernel<<<256, 256, 0, stream>>>(pooled, fwm1, fb1, fc1h);
    fc2_kernel<<<64, 256, 0, stream>>>(fc1h, fwm2, fb2, out);
}

// Round 17
// 404.186 us; speedup vs baseline: 1.1383x; 1.1383x over previous
//
#include <hip/hip_runtime.h>
#include <stdint.h>

// ---------------------------------------------------------------------------
// Net_27891517620298: edge-popup supermask CNN forward.
// R16: R14 verbatim (the measured best: 438 us) + ONE isolated change:
// hist11 grid 128 -> 256 blocks (1 block/CU; the 8-MB score scans were
// running on half the chip). PSTR=40 confirmed (34/36 both -> ~8x conflicts).
// ---------------------------------------------------------------------------

typedef __attribute__((ext_vector_type(8))) short short8;
typedef __attribute__((ext_vector_type(4))) short short4v;
typedef __attribute__((ext_vector_type(4))) float floatx4;

__device__ __forceinline__ unsigned short f2bf(float f) {
    unsigned u = __float_as_uint(f);
    u += 0x7fffu + ((u >> 16) & 1u);   // round-to-nearest-even
    return (unsigned short)(u >> 16);
}

// ---------------- exact top-k selection: 3-pass 11/11/9-bit radix -----------
constexpr unsigned CUM0 = 3456u;
constexpr unsigned CUM1 = 298368u;
constexpr unsigned CUM2 = 1478016u;
constexpr unsigned CUM3 = 2002304u;
constexpr unsigned STOT = 2012544u;
constexpr int NBH = 256;   // 1 block/CU (was 128 = half the chip idle)

__device__ __forceinline__ int find_tensor(unsigned idx, unsigned& li) {
    if (idx < CUM0) { li = idx;        return 0; }
    if (idx < CUM1) { li = idx - CUM0; return 1; }
    if (idx < CUM2) { li = idx - CUM1; return 2; }
    if (idx < CUM3) { li = idx - CUM2; return 3; }
    li = idx - CUM3; return 4;
}

// Pass p histograms: p0 bins key>>20 (2048), p1 bins (key>>9)&2047 filtered by
// 11-bit prefix, p2 bins key&511 filtered by 22-bit prefix. Per-block LDS
// histogram (LDS atomics), nonzero bins flushed to ghist via device atomics.
__global__ __launch_bounds__(256) void hist11(const float* __restrict__ s0,
                                              const float* __restrict__ s1,
                                              const float* __restrict__ s2,
                                              const float* __restrict__ s3,
                                              const float* __restrict__ s4,
                                              const unsigned* __restrict__ P,
                                              unsigned* __restrict__ ghist, int pass) {
    __shared__ unsigned lh[10240];   // up to 2048 bins x 5 tensors
    const int tid = threadIdx.x;
    const int NB = (pass == 2) ? 512 : 2048;
    for (int i = tid; i < NB * 5; i += 256) lh[i] = 0;
    __syncthreads();

    unsigned pref[5];
    #pragma unroll
    for (int t = 0; t < 5; t++) pref[t] = pass ? P[t] : 0u;
    const int fsh = (pass == 1) ? 20 : 9;   // filter shift for pass>=1

    for (unsigned idx = blockIdx.x * 256u + tid; idx < STOT; idx += NBH * 256u) {
        unsigned li; int t = find_tensor(idx, li);
        const float* sp = t == 0 ? s0 : t == 1 ? s1 : t == 2 ? s2 : t == 3 ? s3 : s4;
        unsigned key = __float_as_uint(sp[li]) & 0x7fffffffu;
        bool ok = (pass == 0) || ((key >> fsh) == pref[t]);
        if (ok) {
            unsigned bin = (pass == 0) ? (key >> 20)
                         : (pass == 1) ? ((key >> 9) & 2047u)
                                       : (key & 511u);
            atomicAdd(&lh[(unsigned)t * NB + bin], 1u);
        }
    }
    __syncthreads();
    const int goff = (pass == 0) ? 0 : (pass == 1) ? 10240 : 20480;
    for (int i = tid; i < NB * 5; i += 256) {
        unsigned v = lh[i];
        if (v) atomicAdd(&ghist[goff + i], v);
    }
}

// One block per tensor: segment-parallel quantile locate over NB bins.
__global__ __launch_bounds__(256) void find11(const unsigned* __restrict__ ghist,
                                              unsigned* __restrict__ P,
                                              unsigned* __restrict__ targ, int pass) {
    const int t = blockIdx.x;
    const int tid = threadIdx.x;
    const int NB = (pass == 2) ? 512 : 2048;
    const int goff = (pass == 0) ? 0 : (pass == 1) ? 10240 : 20480;
    const int seg = NB / 256;   // 8 or 2
    __shared__ unsigned bins[2048];
    __shared__ unsigned part[256];
    for (int i = tid; i < NB; i += 256) bins[i] = ghist[goff + t * NB + i];
    __syncthreads();
    unsigned s = 0;
    for (int j = 0; j < seg; j++) s += bins[tid * seg + j];
    part[tid] = s;
    __syncthreads();
    if (tid == 0) {
        unsigned n = t == 0 ? 3456u : t == 1 ? 294912u : t == 2 ? 1179648u
                   : t == 3 ? 524288u : 10240u;
        unsigned target = (pass == 0) ? (n >> 1) : targ[t];
        unsigned cum = 0; int q = 0;
        for (; q < 256; q++) { unsigned c = part[q]; if (cum + c > target) break; cum += c; }
        int b = q * seg;
        for (;; b++) { unsigned c = bins[b]; if (cum + c > target) break; cum += c; }
        targ[t] = target - cum;
        if (pass == 0)      P[t] = (unsigned)b;
        else if (pass == 1) P[t] = (P[t] << 11) | (unsigned)b;
        else                P[t] = (P[t] << 9) | (unsigned)b;
    }
}

// Fused: mask by threshold; conv1/fc weights stay fp32; conv2/3 weights go
// bf16 in MFMA-friendly [e][k][c] layout. Also zeroes `pooled`.
__global__ void mask_reorder(const float* __restrict__ w0, const float* __restrict__ w1,
                             const float* __restrict__ w2, const float* __restrict__ w3,
                             const float* __restrict__ w4,
                             const float* __restrict__ s0, const float* __restrict__ s1,
                             const float* __restrict__ s2, const float* __restrict__ s3,
                             const float* __restrict__ s4,
                             const unsigned* __restrict__ T,
                             float* __restrict__ wm1,
                             unsigned short* __restrict__ A2,
                             unsigned short* __restrict__ A3,
                             float* __restrict__ fwm1, float* __restrict__ fwm2,
                             float* __restrict__ pooled) {
    unsigned idx = blockIdx.x * 256u + threadIdx.x;
    if (idx >= STOT) return;
    if (idx < 32768u) pooled[idx] = 0.f;
    unsigned li; int t = find_tensor(idx, li);
    const float* sp = t == 0 ? s0 : t == 1 ? s1 : t == 2 ? s2 : t == 3 ? s3 : s4;
    const float* wp = t == 0 ? w0 : t == 1 ? w1 : t == 2 ? w2 : t == 3 ? w3 : w4;
    unsigned key = __float_as_uint(sp[li]) & 0x7fffffffu;
    float val = (key >= T[t]) ? wp[li] : 0.f;
    if (t == 0) {
        wm1[li] = val;
    } else if (t == 1) {           // w2 [256][128][3][3] -> A2 [e][256][128]
        unsigned k = li / 1152u, r = li - k * 1152u;
        unsigned c = r / 9u, e = r - c * 9u;
        A2[((size_t)e * 256u + k) * 128u + c] = f2bf(val);
    } else if (t == 2) {           // w3 [512][256][3][3] -> A3 [e][512][256]
        unsigned k = li / 2304u, r = li - k * 2304u;
        unsigned c = r / 9u, e = r - c * 9u;
        A3[((size_t)e * 512u + k) * 256u + c] = f2bf(val);
    } else if (t == 3) {
        fwm1[li] = val;
    } else {
        fwm2[li] = val;
    }
}

// ---------------- conv1: direct 3x3 fp32 -> bf16 NHWC -----------------------
template <int C, int H, int W, int K, int TX, int TY, int KT>
__global__ __launch_bounds__(TX* TY) void conv_direct(const float* __restrict__ in,
                                                      const float* __restrict__ wm,
                                                      const float* __restrict__ bias,
                                                      unsigned short* __restrict__ out) {
    constexpr int TILW = TX * 2, TILH = TY * 2;
    constexpr int ITW = TILW + 2, ITH = TILH + 2;
    constexpr int NTHREADS = TX * TY;
    constexpr int NLOAD = (ITH * ITW + NTHREADS - 1) / NTHREADS;
    constexpr int KG = K / KT;

    __shared__ float sIn[ITH * ITW];
    __shared__ float sW[9 * KT];

    const int tid = threadIdx.x;
    const int tx = tid % TX, ty = tid / TX;
    const int kg = blockIdx.z % KG, n = blockIdx.z / KG;
    const int ox0 = blockIdx.x * TILW, oy0 = blockIdx.y * TILH;
    const int ix0 = ox0 - 1, iy0 = oy0 - 1;

    const float* inN = in + (size_t)n * C * H * W;
    const float* wkg = wm + (size_t)kg * KT * C * 9;

    int goff[NLOAD];
    #pragma unroll
    for (int i = 0; i < NLOAD; i++) {
        int idx = tid + i * NTHREADS;
        if (idx < ITH * ITW) {
            int r = idx / ITW, col = idx % ITW;
            int gy = iy0 + r, gx = ix0 + col;
            goff[i] = (gy >= 0 && gy < H && gx >= 0 && gx < W) ? (gy * W + gx) : -1;
        } else goff[i] = -2;
    }

    float acc[2][2][KT];
    #pragma unroll
    for (int py = 0; py < 2; py++)
        #pragma unroll
        for (int px = 0; px < 2; px++)
            #pragma unroll
            for (int j = 0; j < KT; j++) acc[py][px][j] = 0.f;

    for (int c = 0; c < C; c++) {
        const float* inC = inN + (size_t)c * H * W;
        #pragma unroll
        for (int i = 0; i < NLOAD; i++) {
            int g = goff[i];
            if (g >= -1) sIn[tid + i * NTHREADS] = (g >= 0) ? inC[g] : 0.f;
        }
        for (int i = tid; i < 9 * KT; i += NTHREADS) {
            int e = i / KT, j = i % KT;
            sW[i] = wkg[j * C * 9 + c * 9 + e];
        }
        __syncthreads();

        float vin[4][4];
        const float* base = &sIn[(ty * 2) * ITW + tx * 2];
        #pragma unroll
        for (int r = 0; r < 4; r++)
            #pragma unroll
            for (int cc = 0; cc < 4; cc++) vin[r][cc] = base[r * ITW + cc];

        #pragma unroll
        for (int e = 0; e < 9; e++) {
            const int dy = e / 3, dx = e % 3;
            #pragma unroll
            for (int j = 0; j < KT; j++) {
                float wv = sW[e * KT + j];
                #pragma unroll
                for (int py = 0; py < 2; py++)
                    #pragma unroll
                    for (int px = 0; px < 2; px++)
                        acc[py][px][j] = fmaf(vin[py + dy][px + dx], wv, acc[py][px][j]);
            }
        }
        __syncthreads();
    }

    float bj[KT];
    #pragma unroll
    for (int j = 0; j < KT; j++) bj[j] = bias[kg * KT + j];
    #pragma unroll
    for (int py = 0; py < 2; py++)
        #pragma unroll
        for (int px = 0; px < 2; px++) {
            int oy = oy0 + ty * 2 + py, ox = ox0 + tx * 2 + px;
            short8 v;
            #pragma unroll
            for (int j = 0; j < KT; j++) {
                float t = acc[py][px][j] + bj[j];
                v[j] = (short)f2bf(t > 0.f ? t : 0.f);
            }
            *(short8*)(out + ((size_t)(n * H + oy) * W + ox) * K + kg * KT) = v;
        }
}

// ---------------- conv2/conv3: NHWC MFMA, B in LDS, A prefetched (R9) -------
// stride-2 3x3 conv, bf16 NHWC input. Block = 4 waves; tile 128 k x 128 pix.
// Wave: 32 k (2 fm) x 128 pix (8 fn). Per 32-ch chunk: stage input tile once
// (the ONLY barriers: 2 per chunk), then 9 taps x {8 B ds_read_b128, 16 MFMA}
// with A-frags (2/tap) global->VGPR prefetched one tap ahead (L2-resident).
// PSTR=40 (measured-best; 34/36 both gave ~8x bank conflicts). Grid
// dim3(pt,kb,n): input-sharing pairs are 8 apart in linear id -> same XCD
// (measured: FETCH 57 vs 135 MB for kb-fastest ordering).
template <int C, int H, int W, int KOUT, bool POOL>
__global__ __launch_bounds__(256) void conv_mfma(const unsigned short* __restrict__ in,
                                                 const unsigned short* __restrict__ A,
                                                 const float* __restrict__ bias,
                                                 void* __restrict__ outv) {
    constexpr int OH = H / 2, OW = W / 2;
    constexpr int PR = 128 / OW;          // output rows per 128-pixel tile
    constexpr int RH = 2 * PR + 1;        // input rows needed
    constexpr int IW = W + 1;             // input cols needed
    constexpr int NC = C / 32;
    constexpr int PSTR = 40;              // shorts per pixel (measured-best)
    constexpr int NSLOT = RH * IW * 4;    // 16B staging chunks
    constexpr int SLMAX = (NSLOT + 255) / 256;

    __shared__ unsigned short sIn[RH * IW * PSTR];

    const int tid = threadIdx.x;
    const int lane = tid & 63;
    const int wv = tid >> 6;
    const int l15 = lane & 15;
    const int quad = lane >> 4;
    const int pt = blockIdx.x, kb = blockIdx.y, n = blockIdx.z;
    const int k0 = kb * 128;
    const int oy0 = pt * PR;
    const int g0y = 2 * oy0 - 1;
    const int mw = wv * 32;               // wave's 32 output-channel rows

    // staging slots (chunk-invariant): slot s -> (pix = s>>2, q = s&3)
    int goff[SLMAX], slds[SLMAX];
    #pragma unroll
    for (int i = 0; i < SLMAX; i++) {
        int s = tid + i * 256;
        if (s < NSLOT) {
            int q = s & 3, pix = s >> 2;
            int ix = pix % IW, iy = pix / IW;
            int gy = g0y + iy, gx = ix - 1;
            slds[i] = pix * PSTR + q * 8;
            goff[i] = (gy >= 0 && gy < H && gx >= 0) ? ((gy * W + gx) * C + q * 8) : -1;
        } else { goff[i] = -2; slds[i] = 0; }
    }

    // B-frag pixel bases: frag fn = pixels fn*16 + l15
    int pB[8];
    #pragma unroll
    for (int fn = 0; fn < 8; fn++) {
        int p = fn * 16 + l15;
        int oyl = p / OW, oxl = p % OW;
        pB[fn] = (oyl * 2 * IW + oxl * 2) * PSTR + quad * 8;
    }

    const unsigned short* inN = in + (size_t)n * H * W * C;

    floatx4 acc[2][8];
    #pragma unroll
    for (int fm = 0; fm < 2; fm++)
        #pragma unroll
        for (int fn = 0; fn < 8; fn++) acc[fm][fn] = (floatx4){0.f, 0.f, 0.f, 0.f};

    for (int cc = 0; cc < NC; cc++) {
        __syncthreads();   // previous chunk's readers done
        const int cof = cc * 32;
        #pragma unroll
        for (int i = 0; i < SLMAX; i++) {
            int g = goff[i];
            if (g >= 0) {
                *(short8*)&sIn[slds[i]] = *(const short8*)(inN + g + cof);
            } else if (g == -1 && cc == 0) {
                *(short8*)&sIn[slds[i]] = (short8){0, 0, 0, 0, 0, 0, 0, 0};
            }
        }
        __syncthreads();

        // A-frag base for this wave/lane: A[e][k0+mw+l15+fm*16][cof+quad*8]
        const unsigned short* Abase = A + (size_t)(k0 + mw + l15) * C + cof + quad * 8;
        const size_t estr = (size_t)KOUT * C;

        // prefetch tap 0
        short8 a0 = *(const short8*)(Abase);
        short8 a1 = *(const short8*)(Abase + 16 * C);

        #pragma unroll 1
        for (int e = 0; e < 9; e++) {
            short8 ac0 = a0, ac1 = a1;
            if (e < 8) {   // prefetch next tap while computing this one
                a0 = *(const short8*)(Abase + (size_t)(e + 1) * estr);
                a1 = *(const short8*)(Abase + (size_t)(e + 1) * estr + 16 * C);
            }
            const int dy = e / 3, dx = e - dy * 3;
            const int boff = (dy * IW + dx) * PSTR;
            short8 bfr[8];
            #pragma unroll
            for (int fn = 0; fn < 8; fn++)
                bfr[fn] = *(const short8*)&sIn[pB[fn] + boff];
            #pragma unroll
            for (int fn = 0; fn < 8; fn++) {
                acc[0][fn] = __builtin_amdgcn_mfma_f32_16x16x32_bf16(ac0, bfr[fn], acc[0][fn], 0, 0, 0);
                acc[1][fn] = __builtin_amdgcn_mfma_f32_16x16x32_bf16(ac1, bfr[fn], acc[1][fn], 0, 0, 0);
            }
        }
    }

    if (!POOL) {
        unsigned short* out = (unsigned short*)outv;
        #pragma unroll
        for (int fm = 0; fm < 2; fm++) {
            const int k4 = k0 + mw + fm * 16 + quad * 4;
            float b0 = bias[k4], b1 = bias[k4 + 1], b2 = bias[k4 + 2], b3 = bias[k4 + 3];
            #pragma unroll
            for (int fn = 0; fn < 8; fn++) {
                int p = fn * 16 + l15;
                int oy = oy0 + p / OW, ox = p % OW;
                float v0 = acc[fm][fn][0] + b0, v1 = acc[fm][fn][1] + b1;
                float v2 = acc[fm][fn][2] + b2, v3 = acc[fm][fn][3] + b3;
                short4v v;
                v[0] = (short)f2bf(v0 > 0.f ? v0 : 0.f);
                v[1] = (short)f2bf(v1 > 0.f ? v1 : 0.f);
                v[2] = (short)f2bf(v2 > 0.f ? v2 : 0.f);
                v[3] = (short)f2bf(v3 > 0.f ? v3 : 0.f);
                *(short4v*)(out + ((size_t)(n * OH + oy) * OW + ox) * KOUT + k4) = v;
            }
        }
    } else {
        float* out = (float*)outv;
        #pragma unroll
        for (int fm = 0; fm < 2; fm++) {
            #pragma unroll
            for (int reg = 0; reg < 4; reg++) {
                int k = k0 + mw + fm * 16 + quad * 4 + reg;
                float bv = bias[k];
                float s = 0.f;
                #pragma unroll
                for (int fn = 0; fn < 8; fn++) {
                    float v = acc[fm][fn][reg] + bv;
                    s += v > 0.f ? v : 0.f;
                }
                s += __shfl_xor(s, 1); s += __shfl_xor(s, 2);
                s += __shfl_xor(s, 4); s += __shfl_xor(s, 8);
                if (l15 == 0) atomicAdd(&out[n * KOUT + k], s * (1.0f / (OH * OW)));
            }
        }
    }
}

// ---------------- FCs (fp32, tiny; R9 versions) -----------------------------
__global__ void fc1_kernel(const float* __restrict__ pooled, const float* __restrict__ w,
                           const float* __restrict__ b, float* __restrict__ out) {
    int t = blockIdx.x * 256 + threadIdx.x;
    int o = t & 1023, n = t >> 10;
    const float4* w4 = (const float4*)(w + (size_t)o * 512);
    const float4* p4 = (const float4*)(pooled + (size_t)n * 512);
    float acc = 0.f;
    for (int i = 0; i < 128; i++) {
        float4 a = p4[i], ww = w4[i];
        acc += a.x * ww.x + a.y * ww.y + a.z * ww.z + a.w * ww.w;
    }
    acc += b[o];
    out[t] = acc > 0.f ? acc : 0.f;
}

__global__ void fc2_kernel(const float* __restrict__ h, const float* __restrict__ w,
                           const float* __restrict__ b, float* __restrict__ out) {
    int n = blockIdx.x, tid = threadIdx.x;
    __shared__ float redw[40];
    const float4* h4 = (const float4*)(h + (size_t)n * 1024);
    float4 a = h4[tid];
    for (int o = 0; o < 10; o++) {
        const float4* w4 = (const float4*)(w + (size_t)o * 1024);
        float4 ww = w4[tid];
        float v = a.x * ww.x + a.y * ww.y + a.z * ww.z + a.w * ww.w;
        for (int off = 32; off > 0; off >>= 1) v += __shfl_down(v, off);
        if ((tid & 63) == 0) redw[o * 4 + (tid >> 6)] = v;
    }
    __syncthreads();
    if (tid < 10) {
        float s = redw[tid * 4] + redw[tid * 4 + 1] + redw[tid * 4 + 2] + redw[tid * 4 + 3] + b[tid];
        out[n * 10 + tid] = s;
    }
}

extern "C" void kernel_launch(void* const* d_in, const int* in_sizes, int n_in,
                              void* d_out, int out_size, void* d_ws, size_t ws_size,
                              hipStream_t stream) {
    const float* x   = (const float*)d_in[0];
    const float* w1  = (const float*)d_in[1];
    const float* s1  = (const float*)d_in[2];
    const float* b1  = (const float*)d_in[3];
    const float* w2  = (const float*)d_in[4];
    const float* s2  = (const float*)d_in[5];
    const float* b2  = (const float*)d_in[6];
    const float* w3  = (const float*)d_in[7];
    const float* s3  = (const float*)d_in[8];
    const float* b3  = (const float*)d_in[9];
    const float* fw1 = (const float*)d_in[10];
    const float* fs1 = (const float*)d_in[11];
    const float* fb1 = (const float*)d_in[12];
    const float* fw2 = (const float*)d_in[13];
    const float* fs2 = (const float*)d_in[14];
    const float* fb2 = (const float*)d_in[15];
    float* out = (float*)d_out;

    char* ws = (char*)d_ws;
    size_t off = 0;
    auto alloc = [&](size_t bytes) -> char* {
        char* p = ws + off;
        off = (off + bytes + 255) & ~(size_t)255;
        return p;
    };
    unsigned* ghist = (unsigned*)alloc(23040ull * 4);   // 2048*5 + 2048*5 + 512*5
    unsigned* P     = (unsigned*)alloc(64);
    unsigned* targ  = (unsigned*)alloc(64);
    float* wm1  = (float*)alloc(3456ull * 4);
    float* fwm1 = (float*)alloc(524288ull * 4);
    float* fwm2 = (float*)alloc(10240ull * 4);
    unsigned short* A2 = (unsigned short*)alloc(294912ull * 2);   // bf16 [9][256][128]
    unsigned short* A3 = (unsigned short*)alloc(1179648ull * 2);  // bf16 [9][512][256]
    unsigned short* h1 = (unsigned short*)alloc(33554432ull * 2); // bf16 NHWC 64x64x64x128
    unsigned short* h2 = (unsigned short*)alloc(16777216ull * 2); // bf16 NHWC 64x32x32x256
    float* pooled = (float*)alloc(32768ull * 4);                  // 64x512
    float* fc1h   = (float*)alloc(65536ull * 4);                  // 64x1024
    if (off > ws_size) return;

    (void)hipMemsetAsync(ghist, 0, 23040ull * 4, stream);

    for (int pass = 0; pass < 3; pass++) {
        hist11<<<NBH, 256, 0, stream>>>(s1, s2, s3, fs1, fs2, P, ghist, pass);
        find11<<<5, 256, 0, stream>>>(ghist, P, targ, pass);
    }
    int gs = (STOT + 255) / 256;
    mask_reorder<<<gs, 256, 0, stream>>>(w1, w2, w3, fw1, fw2, s1, s2, s3, fs1, fs2, P,
                                         wm1, A2, A3, fwm1, fwm2, pooled);

    // conv1: 3->128, 64x64, stride 1, direct fp32 -> bf16 NHWC h1
    conv_direct<3, 64, 64, 128, 16, 16, 8>
        <<<dim3(2, 2, 64 * 16), 256, 0, stream>>>(x, wm1, b1, h1);
    // conv2: 128->256, 64x64 -> 32x32 NHWC. 8 pixel tiles x 2 k tiles x 64 n
    conv_mfma<128, 64, 64, 256, false>
        <<<dim3(8, 2, 64), 256, 0, stream>>>(h1, A2, b2, h2);
    // conv3: 256->512, 32x32 -> 16x16, fused GAP. 2 pixel tiles x 4 k x 64 n
    conv_mfma<256, 32, 32, 512, true>
        <<<dim3(2, 4, 64), 256, 0, stream>>>(h2, A3, b3, pooled);

    fc1_kernel<<<256, 256, 0, stream>>>(pooled, fwm1, fb1, fc1h);
    fc2_kernel<<<64, 256, 0, stream>>>(fc1h, fwm2, fb2, out);
}

// Round 18
// 398.216 us; speedup vs baseline: 1.1553x; 1.0150x over previous
//
#include <hip/hip_runtime.h>
#include <stdint.h>

// ---------------------------------------------------------------------------
// Net_27891517620298: edge-popup supermask CNN forward.
// R17: R16 verbatim + ONE isolated change: hist11 grid 256 -> 512 blocks
// (2 blocks/CU, 8 waves: the score scan is latency-bound and scaled ~2x with
// blocks at 128->256). PSTR=40 and dim3(8,2,64)/(2,4,64) grids confirmed.
// ---------------------------------------------------------------------------

typedef __attribute__((ext_vector_type(8))) short short8;
typedef __attribute__((ext_vector_type(4))) short short4v;
typedef __attribute__((ext_vector_type(4))) float floatx4;

__device__ __forceinline__ unsigned short f2bf(float f) {
    unsigned u = __float_as_uint(f);
    u += 0x7fffu + ((u >> 16) & 1u);   // round-to-nearest-even
    return (unsigned short)(u >> 16);
}

// ---------------- exact top-k selection: 3-pass 11/11/9-bit radix -----------
constexpr unsigned CUM0 = 3456u;
constexpr unsigned CUM1 = 298368u;
constexpr unsigned CUM2 = 1478016u;
constexpr unsigned CUM3 = 2002304u;
constexpr unsigned STOT = 2012544u;
constexpr int NBH = 512;   // 2 blocks/CU (LDS 40 KB allows 4)

__device__ __forceinline__ int find_tensor(unsigned idx, unsigned& li) {
    if (idx < CUM0) { li = idx;        return 0; }
    if (idx < CUM1) { li = idx - CUM0; return 1; }
    if (idx < CUM2) { li = idx - CUM1; return 2; }
    if (idx < CUM3) { li = idx - CUM2; return 3; }
    li = idx - CUM3; return 4;
}

// Pass p histograms: p0 bins key>>20 (2048), p1 bins (key>>9)&2047 filtered by
// 11-bit prefix, p2 bins key&511 filtered by 22-bit prefix. Per-block LDS
// histogram (LDS atomics), nonzero bins flushed to ghist via device atomics.
__global__ __launch_bounds__(256) void hist11(const float* __restrict__ s0,
                                              const float* __restrict__ s1,
                                              const float* __restrict__ s2,
                                              const float* __restrict__ s3,
                                              const float* __restrict__ s4,
                                              const unsigned* __restrict__ P,
                                              unsigned* __restrict__ ghist, int pass) {
    __shared__ unsigned lh[10240];   // up to 2048 bins x 5 tensors
    const int tid = threadIdx.x;
    const int NB = (pass == 2) ? 512 : 2048;
    for (int i = tid; i < NB * 5; i += 256) lh[i] = 0;
    __syncthreads();

    unsigned pref[5];
    #pragma unroll
    for (int t = 0; t < 5; t++) pref[t] = pass ? P[t] : 0u;
    const int fsh = (pass == 1) ? 20 : 9;   // filter shift for pass>=1

    for (unsigned idx = blockIdx.x * 256u + tid; idx < STOT; idx += NBH * 256u) {
        unsigned li; int t = find_tensor(idx, li);
        const float* sp = t == 0 ? s0 : t == 1 ? s1 : t == 2 ? s2 : t == 3 ? s3 : s4;
        unsigned key = __float_as_uint(sp[li]) & 0x7fffffffu;
        bool ok = (pass == 0) || ((key >> fsh) == pref[t]);
        if (ok) {
            unsigned bin = (pass == 0) ? (key >> 20)
                         : (pass == 1) ? ((key >> 9) & 2047u)
                                       : (key & 511u);
            atomicAdd(&lh[(unsigned)t * NB + bin], 1u);
        }
    }
    __syncthreads();
    const int goff = (pass == 0) ? 0 : (pass == 1) ? 10240 : 20480;
    for (int i = tid; i < NB * 5; i += 256) {
        unsigned v = lh[i];
        if (v) atomicAdd(&ghist[goff + i], v);
    }
}

// One block per tensor: segment-parallel quantile locate over NB bins.
__global__ __launch_bounds__(256) void find11(const unsigned* __restrict__ ghist,
                                              unsigned* __restrict__ P,
                                              unsigned* __restrict__ targ, int pass) {
    const int t = blockIdx.x;
    const int tid = threadIdx.x;
    const int NB = (pass == 2) ? 512 : 2048;
    const int goff = (pass == 0) ? 0 : (pass == 1) ? 10240 : 20480;
    const int seg = NB / 256;   // 8 or 2
    __shared__ unsigned bins[2048];
    __shared__ unsigned part[256];
    for (int i = tid; i < NB; i += 256) bins[i] = ghist[goff + t * NB + i];
    __syncthreads();
    unsigned s = 0;
    for (int j = 0; j < seg; j++) s += bins[tid * seg + j];
    part[tid] = s;
    __syncthreads();
    if (tid == 0) {
        unsigned n = t == 0 ? 3456u : t == 1 ? 294912u : t == 2 ? 1179648u
                   : t == 3 ? 524288u : 10240u;
        unsigned target = (pass == 0) ? (n >> 1) : targ[t];
        unsigned cum = 0; int q = 0;
        for (; q < 256; q++) { unsigned c = part[q]; if (cum + c > target) break; cum += c; }
        int b = q * seg;
        for (;; b++) { unsigned c = bins[b]; if (cum + c > target) break; cum += c; }
        targ[t] = target - cum;
        if (pass == 0)      P[t] = (unsigned)b;
        else if (pass == 1) P[t] = (P[t] << 11) | (unsigned)b;
        else                P[t] = (P[t] << 9) | (unsigned)b;
    }
}

// Fused: mask by threshold; conv1/fc weights stay fp32; conv2/3 weights go
// bf16 in MFMA-friendly [e][k][c] layout. Also zeroes `pooled`.
__global__ void mask_reorder(const float* __restrict__ w0, const float* __restrict__ w1,
                             const float* __restrict__ w2, const float* __restrict__ w3,
                             const float* __restrict__ w4,
                             const float* __restrict__ s0, const float* __restrict__ s1,
                             const float* __restrict__ s2, const float* __restrict__ s3,
                             const float* __restrict__ s4,
                             const unsigned* __restrict__ T,
                             float* __restrict__ wm1,
                             unsigned short* __restrict__ A2,
                             unsigned short* __restrict__ A3,
                             float* __restrict__ fwm1, float* __restrict__ fwm2,
                             float* __restrict__ pooled) {
    unsigned idx = blockIdx.x * 256u + threadIdx.x;
    if (idx >= STOT) return;
    if (idx < 32768u) pooled[idx] = 0.f;
    unsigned li; int t = find_tensor(idx, li);
    const float* sp = t == 0 ? s0 : t == 1 ? s1 : t == 2 ? s2 : t == 3 ? s3 : s4;
    const float* wp = t == 0 ? w0 : t == 1 ? w1 : t == 2 ? w2 : t == 3 ? w3 : w4;
    unsigned key = __float_as_uint(sp[li]) & 0x7fffffffu;
    float val = (key >= T[t]) ? wp[li] : 0.f;
    if (t == 0) {
        wm1[li] = val;
    } else if (t == 1) {           // w2 [256][128][3][3] -> A2 [e][256][128]
        unsigned k = li / 1152u, r = li - k * 1152u;
        unsigned c = r / 9u, e = r - c * 9u;
        A2[((size_t)e * 256u + k) * 128u + c] = f2bf(val);
    } else if (t == 2) {           // w3 [512][256][3][3] -> A3 [e][512][256]
        unsigned k = li / 2304u, r = li - k * 2304u;
        unsigned c = r / 9u, e = r - c * 9u;
        A3[((size_t)e * 512u + k) * 256u + c] = f2bf(val);
    } else if (t == 3) {
        fwm1[li] = val;
    } else {
        fwm2[li] = val;
    }
}

// ---------------- conv1: direct 3x3 fp32 -> bf16 NHWC -----------------------
template <int C, int H, int W, int K, int TX, int TY, int KT>
__global__ __launch_bounds__(TX* TY) void conv_direct(const float* __restrict__ in,
                                                      const float* __restrict__ wm,
                                                      const float* __restrict__ bias,
                                                      unsigned short* __restrict__ out) {
    constexpr int TILW = TX * 2, TILH = TY * 2;
    constexpr int ITW = TILW + 2, ITH = TILH + 2;
    constexpr int NTHREADS = TX * TY;
    constexpr int NLOAD = (ITH * ITW + NTHREADS - 1) / NTHREADS;
    constexpr int KG = K / KT;

    __shared__ float sIn[ITH * ITW];
    __shared__ float sW[9 * KT];

    const int tid = threadIdx.x;
    const int tx = tid % TX, ty = tid / TX;
    const int kg = blockIdx.z % KG, n = blockIdx.z / KG;
    const int ox0 = blockIdx.x * TILW, oy0 = blockIdx.y * TILH;
    const int ix0 = ox0 - 1, iy0 = oy0 - 1;

    const float* inN = in + (size_t)n * C * H * W;
    const float* wkg = wm + (size_t)kg * KT * C * 9;

    int goff[NLOAD];
    #pragma unroll
    for (int i = 0; i < NLOAD; i++) {
        int idx = tid + i * NTHREADS;
        if (idx < ITH * ITW) {
            int r = idx / ITW, col = idx % ITW;
            int gy = iy0 + r, gx = ix0 + col;
            goff[i] = (gy >= 0 && gy < H && gx >= 0 && gx < W) ? (gy * W + gx) : -1;
        } else goff[i] = -2;
    }

    float acc[2][2][KT];
    #pragma unroll
    for (int py = 0; py < 2; py++)
        #pragma unroll
        for (int px = 0; px < 2; px++)
            #pragma unroll
            for (int j = 0; j < KT; j++) acc[py][px][j] = 0.f;

    for (int c = 0; c < C; c++) {
        const float* inC = inN + (size_t)c * H * W;
        #pragma unroll
        for (int i = 0; i < NLOAD; i++) {
            int g = goff[i];
            if (g >= -1) sIn[tid + i * NTHREADS] = (g >= 0) ? inC[g] : 0.f;
        }
        for (int i = tid; i < 9 * KT; i += NTHREADS) {
            int e = i / KT, j = i % KT;
            sW[i] = wkg[j * C * 9 + c * 9 + e];
        }
        __syncthreads();

        float vin[4][4];
        const float* base = &sIn[(ty * 2) * ITW + tx * 2];
        #pragma unroll
        for (int r = 0; r < 4; r++)
            #pragma unroll
            for (int cc = 0; cc < 4; cc++) vin[r][cc] = base[r * ITW + cc];

        #pragma unroll
        for (int e = 0; e < 9; e++) {
            const int dy = e / 3, dx = e % 3;
            #pragma unroll
            for (int j = 0; j < KT; j++) {
                float wv = sW[e * KT + j];
                #pragma unroll
                for (int py = 0; py < 2; py++)
                    #pragma unroll
                    for (int px = 0; px < 2; px++)
                        acc[py][px][j] = fmaf(vin[py + dy][px + dx], wv, acc[py][px][j]);
            }
        }
        __syncthreads();
    }

    float bj[KT];
    #pragma unroll
    for (int j = 0; j < KT; j++) bj[j] = bias[kg * KT + j];
    #pragma unroll
    for (int py = 0; py < 2; py++)
        #pragma unroll
        for (int px = 0; px < 2; px++) {
            int oy = oy0 + ty * 2 + py, ox = ox0 + tx * 2 + px;
            short8 v;
            #pragma unroll
            for (int j = 0; j < KT; j++) {
                float t = acc[py][px][j] + bj[j];
                v[j] = (short)f2bf(t > 0.f ? t : 0.f);
            }
            *(short8*)(out + ((size_t)(n * H + oy) * W + ox) * K + kg * KT) = v;
        }
}

// ---------------- conv2/conv3: NHWC MFMA, B in LDS, A prefetched (R9) -------
// stride-2 3x3 conv, bf16 NHWC input. Block = 4 waves; tile 128 k x 128 pix.
// Wave: 32 k (2 fm) x 128 pix (8 fn). Per 32-ch chunk: stage input tile once
// (the ONLY barriers: 2 per chunk), then 9 taps x {8 B ds_read_b128, 16 MFMA}
// with A-frags (2/tap) global->VGPR prefetched one tap ahead (L2-resident).
// PSTR=40 (measured-best; 34/36 both gave ~8x bank conflicts). Grid
// dim3(pt,kb,n): input-sharing pairs are 8 apart in linear id -> same XCD
// (measured: FETCH 57 vs 135 MB for kb-fastest ordering).
template <int C, int H, int W, int KOUT, bool POOL>
__global__ __launch_bounds__(256) void conv_mfma(const unsigned short* __restrict__ in,
                                                 const unsigned short* __restrict__ A,
                                                 const float* __restrict__ bias,
                                                 void* __restrict__ outv) {
    constexpr int OH = H / 2, OW = W / 2;
    constexpr int PR = 128 / OW;          // output rows per 128-pixel tile
    constexpr int RH = 2 * PR + 1;        // input rows needed
    constexpr int IW = W + 1;             // input cols needed
    constexpr int NC = C / 32;
    constexpr int PSTR = 40;              // shorts per pixel (measured-best)
    constexpr int NSLOT = RH * IW * 4;    // 16B staging chunks
    constexpr int SLMAX = (NSLOT + 255) / 256;

    __shared__ unsigned short sIn[RH * IW * PSTR];

    const int tid = threadIdx.x;
    const int lane = tid & 63;
    const int wv = tid >> 6;
    const int l15 = lane & 15;
    const int quad = lane >> 4;
    const int pt = blockIdx.x, kb = blockIdx.y, n = blockIdx.z;
    const int k0 = kb * 128;
    const int oy0 = pt * PR;
    const int g0y = 2 * oy0 - 1;
    const int mw = wv * 32;               // wave's 32 output-channel rows

    // staging slots (chunk-invariant): slot s -> (pix = s>>2, q = s&3)
    int goff[SLMAX], slds[SLMAX];
    #pragma unroll
    for (int i = 0; i < SLMAX; i++) {
        int s = tid + i * 256;
        if (s < NSLOT) {
            int q = s & 3, pix = s >> 2;
            int ix = pix % IW, iy = pix / IW;
            int gy = g0y + iy, gx = ix - 1;
            slds[i] = pix * PSTR + q * 8;
            goff[i] = (gy >= 0 && gy < H && gx >= 0) ? ((gy * W + gx) * C + q * 8) : -1;
        } else { goff[i] = -2; slds[i] = 0; }
    }

    // B-frag pixel bases: frag fn = pixels fn*16 + l15
    int pB[8];
    #pragma unroll
    for (int fn = 0; fn < 8; fn++) {
        int p = fn * 16 + l15;
        int oyl = p / OW, oxl = p % OW;
        pB[fn] = (oyl * 2 * IW + oxl * 2) * PSTR + quad * 8;
    }

    const unsigned short* inN = in + (size_t)n * H * W * C;

    floatx4 acc[2][8];
    #pragma unroll
    for (int fm = 0; fm < 2; fm++)
        #pragma unroll
        for (int fn = 0; fn < 8; fn++) acc[fm][fn] = (floatx4){0.f, 0.f, 0.f, 0.f};

    for (int cc = 0; cc < NC; cc++) {
        __syncthreads();   // previous chunk's readers done
        const int cof = cc * 32;
        #pragma unroll
        for (int i = 0; i < SLMAX; i++) {
            int g = goff[i];
            if (g >= 0) {
                *(short8*)&sIn[slds[i]] = *(const short8*)(inN + g + cof);
            } else if (g == -1 && cc == 0) {
                *(short8*)&sIn[slds[i]] = (short8){0, 0, 0, 0, 0, 0, 0, 0};
            }
        }
        __syncthreads();

        // A-frag base for this wave/lane: A[e][k0+mw+l15+fm*16][cof+quad*8]
        const unsigned short* Abase = A + (size_t)(k0 + mw + l15) * C + cof + quad * 8;
        const size_t estr = (size_t)KOUT * C;

        // prefetch tap 0
        short8 a0 = *(const short8*)(Abase);
        short8 a1 = *(const short8*)(Abase + 16 * C);

        #pragma unroll 1
        for (int e = 0; e < 9; e++) {
            short8 ac0 = a0, ac1 = a1;
            if (e < 8) {   // prefetch next tap while computing this one
                a0 = *(const short8*)(Abase + (size_t)(e + 1) * estr);
                a1 = *(const short8*)(Abase + (size_t)(e + 1) * estr + 16 * C);
            }
            const int dy = e / 3, dx = e - dy * 3;
            const int boff = (dy * IW + dx) * PSTR;
            short8 bfr[8];
            #pragma unroll
            for (int fn = 0; fn < 8; fn++)
                bfr[fn] = *(const short8*)&sIn[pB[fn] + boff];
            #pragma unroll
            for (int fn = 0; fn < 8; fn++) {
                acc[0][fn] = __builtin_amdgcn_mfma_f32_16x16x32_bf16(ac0, bfr[fn], acc[0][fn], 0, 0, 0);
                acc[1][fn] = __builtin_amdgcn_mfma_f32_16x16x32_bf16(ac1, bfr[fn], acc[1][fn], 0, 0, 0);
            }
        }
    }

    if (!POOL) {
        unsigned short* out = (unsigned short*)outv;
        #pragma unroll
        for (int fm = 0; fm < 2; fm++) {
            const int k4 = k0 + mw + fm * 16 + quad * 4;
            float b0 = bias[k4], b1 = bias[k4 + 1], b2 = bias[k4 + 2], b3 = bias[k4 + 3];
            #pragma unroll
            for (int fn = 0; fn < 8; fn++) {
                int p = fn * 16 + l15;
                int oy = oy0 + p / OW, ox = p % OW;
                float v0 = acc[fm][fn][0] + b0, v1 = acc[fm][fn][1] + b1;
                float v2 = acc[fm][fn][2] + b2, v3 = acc[fm][fn][3] + b3;
                short4v v;
                v[0] = (short)f2bf(v0 > 0.f ? v0 : 0.f);
                v[1] = (short)f2bf(v1 > 0.f ? v1 : 0.f);
                v[2] = (short)f2bf(v2 > 0.f ? v2 : 0.f);
                v[3] = (short)f2bf(v3 > 0.f ? v3 : 0.f);
                *(short4v*)(out + ((size_t)(n * OH + oy) * OW + ox) * KOUT + k4) = v;
            }
        }
    } else {
        float* out = (float*)outv;
        #pragma unroll
        for (int fm = 0; fm < 2; fm++) {
            #pragma unroll
            for (int reg = 0; reg < 4; reg++) {
                int k = k0 + mw + fm * 16 + quad * 4 + reg;
                float bv = bias[k];
                float s = 0.f;
                #pragma unroll
                for (int fn = 0; fn < 8; fn++) {
                    float v = acc[fm][fn][reg] + bv;
                    s += v > 0.f ? v : 0.f;
                }
                s += __shfl_xor(s, 1); s += __shfl_xor(s, 2);
                s += __shfl_xor(s, 4); s += __shfl_xor(s, 8);
                if (l15 == 0) atomicAdd(&out[n * KOUT + k], s * (1.0f / (OH * OW)));
            }
        }
    }
}

// ---------------- FCs (fp32, tiny; R9 versions) -----------------------------
__global__ void fc1_kernel(const float* __restrict__ pooled, const float* __restrict__ w,
                           const float* __restrict__ b, float* __restrict__ out) {
    int t = blockIdx.x * 256 + threadIdx.x;
    int o = t & 1023, n = t >> 10;
    const float4* w4 = (const float4*)(w + (size_t)o * 512);
    const float4* p4 = (const float4*)(pooled + (size_t)n * 512);
    float acc = 0.f;
    for (int i = 0; i < 128; i++) {
        float4 a = p4[i], ww = w4[i];
        acc += a.x * ww.x + a.y * ww.y + a.z * ww.z + a.w * ww.w;
    }
    acc += b[o];
    out[t] = acc > 0.f ? acc : 0.f;
}

__global__ void fc2_kernel(const float* __restrict__ h, const float* __restrict__ w,
                           const float* __restrict__ b, float* __restrict__ out) {
    int n = blockIdx.x, tid = threadIdx.x;
    __shared__ float redw[40];
    const float4* h4 = (const float4*)(h + (size_t)n * 1024);
    float4 a = h4[tid];
    for (int o = 0; o < 10; o++) {
        const float4* w4 = (const float4*)(w + (size_t)o * 1024);
        float4 ww = w4[tid];
        float v = a.x * ww.x + a.y * ww.y + a.z * ww.z + a.w * ww.w;
        for (int off = 32; off > 0; off >>= 1) v += __shfl_down(v, off);
        if ((tid & 63) == 0) redw[o * 4 + (tid >> 6)] = v;
    }
    __syncthreads();
    if (tid < 10) {
        float s = redw[tid * 4] + redw[tid * 4 + 1] + redw[tid * 4 + 2] + redw[tid * 4 + 3] + b[tid];
        out[n * 10 + tid] = s;
    }
}

extern "C" void kernel_launch(void* const* d_in, const int* in_sizes, int n_in,
                              void* d_out, int out_size, void* d_ws, size_t ws_size,
                              hipStream_t stream) {
    const float* x   = (const float*)d_in[0];
    const float* w1  = (const float*)d_in[1];
    const float* s1  = (const float*)d_in[2];
    const float* b1  = (const float*)d_in[3];
    const float* w2  = (const float*)d_in[4];
    const float* s2  = (const float*)d_in[5];
    const float* b2  = (const float*)d_in[6];
    const float* w3  = (const float*)d_in[7];
    const float* s3  = (const float*)d_in[8];
    const float* b3  = (const float*)d_in[9];
    const float* fw1 = (const float*)d_in[10];
    const float* fs1 = (const float*)d_in[11];
    const float* fb1 = (const float*)d_in[12];
    const float* fw2 = (const float*)d_in[13];
    const float* fs2 = (const float*)d_in[14];
    const float* fb2 = (const float*)d_in[15];
    float* out = (float*)d_out;

    char* ws = (char*)d_ws;
    size_t off = 0;
    auto alloc = [&](size_t bytes) -> char* {
        char* p = ws + off;
        off = (off + bytes + 255) & ~(size_t)255;
        return p;
    };
    unsigned* ghist = (unsigned*)alloc(23040ull * 4);   // 2048*5 + 2048*5 + 512*5
    unsigned* P     = (unsigned*)alloc(64);
    unsigned* targ  = (unsigned*)alloc(64);
    float* wm1  = (float*)alloc(3456ull * 4);
    float* fwm1 = (float*)alloc(524288ull * 4);
    float* fwm2 = (float*)alloc(10240ull * 4);
    unsigned short* A2 = (unsigned short*)alloc(294912ull * 2);   // bf16 [9][256][128]
    unsigned short* A3 = (unsigned short*)alloc(1179648ull * 2);  // bf16 [9][512][256]
    unsigned short* h1 = (unsigned short*)alloc(33554432ull * 2); // bf16 NHWC 64x64x64x128
    unsigned short* h2 = (unsigned short*)alloc(16777216ull * 2); // bf16 NHWC 64x32x32x256
    float* pooled = (float*)alloc(32768ull * 4);                  // 64x512
    float* fc1h   = (float*)alloc(65536ull * 4);                  // 64x1024
    if (off > ws_size) return;

    (void)hipMemsetAsync(ghist, 0, 23040ull * 4, stream);

    for (int pass = 0; pass < 3; pass++) {
        hist11<<<NBH, 256, 0, stream>>>(s1, s2, s3, fs1, fs2, P, ghist, pass);
        find11<<<5, 256, 0, stream>>>(ghist, P, targ, pass);
    }
    int gs = (STOT + 255) / 256;
    mask_reorder<<<gs, 256, 0, stream>>>(w1, w2, w3, fw1, fw2, s1, s2, s3, fs1, fs2, P,
                                         wm1, A2, A3, fwm1, fwm2, pooled);

    // conv1: 3->128, 64x64, stride 1, direct fp32 -> bf16 NHWC h1
    conv_direct<3, 64, 64, 128, 16, 16, 8>
        <<<dim3(2, 2, 64 * 16), 256, 0, stream>>>(x, wm1, b1, h1);
    // conv2: 128->256, 64x64 -> 32x32 NHWC. 8 pixel tiles x 2 k tiles x 64 n
    conv_mfma<128, 64, 64, 256, false>
        <<<dim3(8, 2, 64), 256, 0, stream>>>(h1, A2, b2, h2);
    // conv3: 256->512, 32x32 -> 16x16, fused GAP. 2 pixel tiles x 4 k x 64 n
    conv_mfma<256, 32, 32, 512, true>
        <<<dim3(2, 4, 64), 256, 0, stream>>>(h2, A3, b3, pooled);

    fc1_kernel<<<256, 256, 0, stream>>>(pooled, fwm1, fb1, fc1h);
    fc2_kernel<<<64, 256, 0, stream>>>(fc1h, fwm2, fb2, out);
}